// Round 14
// baseline (54.815 us; speedup 1.0000x reference)
//
#include <hip/hip_runtime.h>
#include <cfloat>
#include <cstdint>

// Problem constants (SHAPE=(96,128,128), B=2, C=32, two maxpool(K3,S2,P1) layers)
// Composed pooling: window 7, stride 4, pad 3. Output grid 2 x 24 x 32 x 32 x 32.
#define B_    2
#define OD    24
#define OH    32
#define OW    32
#define NC    32

// tile geometry: 4 x 4 x 4 output cells per block
#define TZ 4
#define TY 4
#define TX 4
#define TCELLS 64
#define NTZ (OD/TZ)                 // 6
#define NTY (OH/TY)                 // 8
#define NTX (OW/TX)                 // 8
#define NTILES (B_*NTZ*NTY*NTX)     // 768 = 3 blocks/CU * 256 CU
#define SUBL  16                    // sub-lists per tile (slot-parallel)
#define SCAP  64                    // entries per sub-list (mean ~27)
#define NCUR  (NTILES*SUBL)         // 12288 cursors (~27 atomics/addr: safe)
#define OVF2  65536

// ---------------- monotone float<->uint transform ----------------
// order-preserving for non-NaN floats; 0 == "never touched" (xform(f)>0 finite f)
__device__ __forceinline__ unsigned xform(float f) {
    unsigned u = __float_as_uint(f);
    return u ^ ((unsigned)((int)u >> 31) | 0x80000000u);
}
__device__ __forceinline__ float unxform(unsigned t) {
    return (t == 0u) ? 0.0f
           : __uint_as_float((t >> 31) ? (t ^ 0x80000000u) : ~t);
}

// ---------------- kernels ----------------

__global__ __launch_bounds__(256) void k_zero(int* __restrict__ cursor,
                                              int* __restrict__ ovf_n) {
    int i = blockIdx.x * blockDim.x + threadIdx.x;
    if (i < NCUR) cursor[i] = 0;
    if (i == 0) *ovf_n = 0;
}

// expansion at bin time: each point appends (rec|fm, cb) to every tile
// sub-list it touches (1..8 tiles, avg ~1.67). Tile-split logic verified
// correct in round 7; cursor spread (12288 addrs) avoids round-7 contention.
__global__ __launch_bounds__(256) void k_bin(const int* __restrict__ coors,
                                             int* __restrict__ cursor,
                                             int2* __restrict__ lists,
                                             int* __restrict__ ovf_n,
                                             int4* __restrict__ ovf, int N) {
    int i = blockIdx.x * blockDim.x + threadIdx.x;
    if (i >= N) return;
    int4 cc = reinterpret_cast<const int4*>(coors)[i];   // b, z, y, x
    const int b = cc.x;
    const int bz = cc.y >> 2, by = cc.z >> 2, bx = cc.w >> 2;
    // mask bit k (k = lz + 2*ly + 4*lx): contributes to cell (bz+lz,by+ly,bx+lx)
    int mask = 0xFF;
    if (!(cc.y & 3) || bz + 1 >= OD) mask &= 0x55;
    if (!(cc.z & 3) || by + 1 >= OH) mask &= 0x33;
    if (!(cc.w & 3) || bx + 1 >= OW) mask &= 0x0F;

    // per-axis primary tile + submask; secondary tile iff the +1 cell crosses
    const int tzA = bz >> 2;  const bool zB = (mask & 0xAA) && ((bz & 3) == 3);
    const int szA = 0x55 | (((bz & 3) == 3) ? 0 : 0xAA);
    const int tyA = by >> 2;  const bool yB = (mask & 0xCC) && ((by & 3) == 3);
    const int syA = 0x33 | (((by & 3) == 3) ? 0 : 0xCC);
    const int txA = bx >> 2;  const bool xB = (mask & 0xF0) && ((bx & 3) == 3);
    const int sxA = 0x0F | (((bx & 3) == 3) ? 0 : 0xF0);

    const int rec = i << 8;
    const int sl  = i & (SUBL - 1);
    for (int az = 0; az <= (int)zB; ++az) {
        const int tz = tzA + az, sz = az ? 0xAA : szA;
        for (int ay = 0; ay <= (int)yB; ++ay) {
            const int ty = tyA + ay, sy = ay ? 0xCC : syA;
            for (int ax = 0; ax <= (int)xB; ++ax) {
                const int tx = txA + ax, sx = ax ? 0xF0 : sxA;
                const int fm = mask & sz & sy & sx;
                if (!fm) continue;
                const int t  = ((b * NTZ + tz) * NTY + ty) * NTX + tx;
                const int cb = (bz - tz * TZ) * (TY * TX) + (by - ty * TY) * TX
                             + (bx - tx * TX);                  // components may be -1
                const int sub = t * SUBL + sl;
                int pos = atomicAdd(&cursor[sub], 1);
                if (pos < SCAP) {
                    lists[sub * SCAP + pos] = make_int2(rec | fm, cb);
                } else {
                    int o = atomicAdd(ovf_n, 1);
                    if (o < OVF2) ovf[o] = make_int4(t, rec | fm, cb, 0);
                }
            }
        }
    }
}

// no build phase: slot s streams its own pre-masked sub-list from global.
// thread = (slot s = tid>>5 of 16, channel c = tid&31)
__global__ __launch_bounds__(512) void k_tile(const float* __restrict__ feat,
                                              const int* __restrict__ cursor,
                                              const int2* __restrict__ lists,
                                              const int* __restrict__ ovf_n,
                                              const int4* __restrict__ ovf,
                                              float4* __restrict__ out4) {
    __shared__ unsigned sm_out[TCELLS * NC];   // 8 KB only

    // XCD-aware swizzle (768 % 8 == 0 -> bijective)
    const int t   = (blockIdx.x & 7) * (NTILES / 8) + (blockIdx.x >> 3);
    const int tid = threadIdx.x;
    const int tx_ = t & (NTX - 1);
    const int ty_ = (t >> 3) & (NTY - 1);
    const int rest = t >> 6;                   // b*NTZ + tz, 0..11
    const int b   = (rest >= NTZ) ? 1 : 0;
    const int tz_ = rest - b * NTZ;
    const int tz0 = tz_ * TZ, ty0 = ty_ * TY, tx0 = tx_ * TX;

    for (int v = tid; v < TCELLS * NC; v += 512) sm_out[v] = 0u;
    __syncthreads();

    const int s = tid >> 5;
    const int c = tid & 31;
    const int sub = t * SUBL + s;
    int cnt = cursor[sub]; if (cnt > SCAP) cnt = SCAP;   // broadcast load
    const int2* L = lists + (size_t)sub * SCAP;

    // main loop: 8-deep ILP over consecutive entries (streaming reads)
    for (int j0 = 0; j0 < cnt; j0 += 8) {
        int2 e[8];
        unsigned tv[8];
#pragma unroll
        for (int u = 0; u < 8; ++u)
            e[u] = (j0 + u < cnt) ? L[j0 + u] : make_int2(0, 0);  // fm=0 -> no-op
#pragma unroll
        for (int u = 0; u < 8; ++u)
            tv[u] = xform(feat[(((unsigned)e[u].x) >> 8) * NC + c]);
#pragma unroll
        for (int u = 0; u < 8; ++u) {
#pragma unroll
            for (int k = 0; k < 8; ++k) {
                const int koff = (k & 1) * (TY * TX) + ((k >> 1) & 1) * TX
                               + ((k >> 2) & 1);
                if ((e[u].x >> k) & 1)
                    atomicMax(&sm_out[(e[u].y + koff) * NC + c], tv[u]);
            }
        }
    }

    // overflow net (expected empty)
    int on = *ovf_n;
    if (on > 0 && s == 0) {
        if (on > OVF2) on = OVF2;
        for (int j = 0; j < on; ++j) {
            int4 e = ovf[j];
            if (e.x != t) continue;
            unsigned tvv = xform(feat[(((unsigned)e.y) >> 8) * NC + c]);
            const int fm = e.y & 0xFF, cb = e.z;
#pragma unroll
            for (int k = 0; k < 8; ++k) {
                const int koff = (k & 1) * (TY * TX) + ((k >> 1) & 1) * TX
                               + ((k >> 2) & 1);
                if ((fm >> k) & 1)
                    atomicMax(&sm_out[(cb + koff) * NC + c], tvv);
            }
        }
    }
    __syncthreads();

    // epilogue: 64 cells x 8 float4 = 512 stores, one per thread
    {
        const int cell = tid >> 3, quad = tid & 7;
        const int i = cell >> 4, jj = (cell >> 2) & 3, l = cell & 3;
        uint4 uv = *(const uint4*)&sm_out[cell * NC + quad * 4];
        float4 o;
        o.x = unxform(uv.x); o.y = unxform(uv.y);
        o.z = unxform(uv.z); o.w = unxform(uv.w);
        out4[(((size_t)(b * OD + tz0 + i) * OH + (ty0 + jj)) * OW
              + (tx0 + l)) * (NC / 4) + quad] = o;
    }
}

// ---------------- launch ----------------
// ws (ints): cursor[12288] | ovf_n[1]+pad[7] | lists[768*16*64*2] | ovf[OVF2*4]

extern "C" void kernel_launch(void* const* d_in, const int* in_sizes, int n_in,
                              void* d_out, int out_size, void* d_ws, size_t ws_size,
                              hipStream_t stream) {
    const float* feat  = (const float*)d_in[0];
    const int*   coors = (const int*)d_in[1];
    const int N = in_sizes[0] / NC;          // 200000
    float4* out4 = (float4*)d_out;           // 1572864 floats

    int*  cursor = (int*)d_ws;                              // NCUR
    int*  ovf_n  = cursor + NCUR;                           // 1 (+7 pad)
    int2* lists  = (int2*)(ovf_n + 8);                      // NTILES*SUBL*SCAP
    int4* ovf    = (int4*)(lists + (size_t)NTILES * SUBL * SCAP);

    k_zero<<<(NCUR + 255) / 256, 256, 0, stream>>>(cursor, ovf_n);
    k_bin <<<(N + 255) / 256, 256, 0, stream>>>(coors, cursor, lists,
                                                ovf_n, ovf, N);
    k_tile<<<NTILES, 512, 0, stream>>>(feat, cursor, (const int2*)lists,
                                       ovf_n, (const int4*)ovf, out4);
}